// Round 1
// 322.036 us; speedup vs baseline: 1.0557x; 1.0557x over previous
//
#include <hip/hip_runtime.h>
#include <hip/hip_bf16.h>

#define HDIM 2048
#define DDIM 128
#define NT 256        // C cols: kv (0..127) | gate (128..255)
#define BM 32
#define BK 128
#define LDK 136       // padded LDS leading dim (272 B rows, 16B-aligned)
#define MT 16384      // B*S rows

typedef __attribute__((ext_vector_type(8))) short bf16x8_t;
typedef __attribute__((ext_vector_type(4))) float f32x4_t;

// ---------------- kernel 0: detect dtype (inline) + transpose/convert weights --------
// fp32 data viewed as u16: low halves have uniform-random "exponent" bits -> huge bf16s.
// genuine bf16 N(0,1) data never has exponent >= 167 (|x| > 2^40).
__global__ void k_prep(const void* __restrict__ w_kv, const void* __restrict__ w_gate,
                       const unsigned short* __restrict__ hidden,
                       int* __restrict__ flag, __hip_bfloat16* __restrict__ Wt) {
  __shared__ int sflag;
  __shared__ float tile[64][65];
  // local dtype detection (every block; deterministic, block-uniform)
  int bad = 0;
  for (int i = threadIdx.x; i < 8192; i += 256)
    bad |= (((hidden[i] >> 7) & 0xFF) >= 167) ? 1 : 0;
  if (threadIdx.x == 0) sflag = 0;
  __syncthreads();
  if (bad) atomicOr(&sflag, 1);
  __syncthreads();
  const int isF32 = sflag;
  if (threadIdx.x == 0 && blockIdx.x == 0 && blockIdx.y == 0 && blockIdx.z == 0)
    *flag = isF32;   // publish for k_gemm / k_compress (stream-ordered)

  const void* src = blockIdx.z ? w_gate : w_kv;
  const int k0 = blockIdx.x * 64;
  const int n0 = blockIdx.y * 64;
  const int tx = threadIdx.x & 63;
  const int ty = threadIdx.x >> 6;  // 0..3
#pragma unroll
  for (int i = 0; i < 16; ++i) {
    int r = i * 4 + ty;
    int idx = (k0 + r) * DDIM + n0 + tx;
    float v = isF32 ? ((const float*)src)[idx]
                    : __bfloat162float(((const __hip_bfloat16*)src)[idx]);
    tile[tx][r] = v;
  }
  __syncthreads();
#pragma unroll
  for (int i = 0; i < 16; ++i) {
    int r = i * 4 + ty;
    Wt[(blockIdx.z * DDIM + n0 + r) * HDIM + k0 + tx] = __float2bfloat16(tile[r][tx]);
  }
}

// ---------------- kernel 1: C[16384][256] = hidden @ [w_kv | w_gate] (bf16 MFMA) ------
// BM=32 x N=256 block tile, 4 waves each 32x64 -> grid 512 = 2 blocks/CU (was 1).
// BK=128: 64 B/lane of A prefetch in flight, 16 k-steps (was 64 barriers pairs).
__global__ __launch_bounds__(256)
void k_gemm(const void* __restrict__ hidden, const __hip_bfloat16* __restrict__ Wt,
            const int* __restrict__ flag, __hip_bfloat16* __restrict__ C) {
  __shared__ __align__(16) __hip_bfloat16 As[BM * LDK];
  const int isF32 = *flag;
  const int tid  = threadIdx.x;
  const int bm0  = blockIdx.x * BM;
  const int wave = tid >> 6;
  const int lane = tid & 63;
  const int wn   = wave * 64;        // this wave's 64 output columns
  const int lrow = lane & 15;
  const int quad = lane >> 4;

  f32x4_t acc[2][4];
#pragma unroll
  for (int i = 0; i < 2; ++i)
#pragma unroll
    for (int j = 0; j < 4; ++j) acc[i][j] = (f32x4_t){0.f, 0.f, 0.f, 0.f};

  // staging role: row = tid>>3 (0..31), k-segment = (tid&7)*16 (16 floats / 16 bf16)
  const int srow = tid >> 3;
  const int skg  = (tid & 7) * 16;
  const float*          Af = (const float*)hidden + (size_t)(bm0 + srow) * HDIM + skg;
  const unsigned short* Ab = (const unsigned short*)hidden + (size_t)(bm0 + srow) * HDIM + skg;

  float4 pa[4];   // fp32-path prefetch: 64 B/lane
  int4   pb[2];   // bf16-path prefetch: 32 B/lane
  if (isF32) {
#pragma unroll
    for (int l = 0; l < 4; ++l) pa[l] = *(const float4*)(Af + 4 * l);
  } else {
#pragma unroll
    for (int l = 0; l < 2; ++l) pb[l] = *(const int4*)(Ab + 8 * l);
  }

  for (int k0 = 0; k0 < HDIM; k0 += BK) {
    __syncthreads();  // previous iteration's LDS reads complete
    if (isF32) {
#pragma unroll
      for (int l = 0; l < 2; ++l) {
        union { int4 v; __hip_bfloat16 h[8]; } u;
        u.h[0] = __float2bfloat16(pa[2*l].x);   u.h[1] = __float2bfloat16(pa[2*l].y);
        u.h[2] = __float2bfloat16(pa[2*l].z);   u.h[3] = __float2bfloat16(pa[2*l].w);
        u.h[4] = __float2bfloat16(pa[2*l+1].x); u.h[5] = __float2bfloat16(pa[2*l+1].y);
        u.h[6] = __float2bfloat16(pa[2*l+1].z); u.h[7] = __float2bfloat16(pa[2*l+1].w);
        *(int4*)(As + srow * LDK + skg + 8 * l) = u.v;
      }
    } else {
#pragma unroll
      for (int l = 0; l < 2; ++l)
        *(int4*)(As + srow * LDK + skg + 8 * l) = pb[l];
    }
    __syncthreads();

    // prefetch next K tile into registers (overlaps with this tile's compute)
    if (k0 + BK < HDIM) {
      if (isF32) {
#pragma unroll
        for (int l = 0; l < 4; ++l) pa[l] = *(const float4*)(Af + k0 + BK + 4 * l);
      } else {
#pragma unroll
        for (int l = 0; l < 2; ++l) pb[l] = *(const int4*)(Ab + k0 + BK + 8 * l);
      }
    }

#pragma unroll
    for (int kk = 0; kk < BK; kk += 32) {
      bf16x8_t afrag[2], bfrag[4];
#pragma unroll
      for (int nt = 0; nt < 4; ++nt)   // B frag: col = lane&15, k = quad*8 + j
        bfrag[nt] = *(const bf16x8_t*)(Wt + (size_t)(wn + nt * 16 + lrow) * HDIM + k0 + kk + quad * 8);
#pragma unroll
      for (int mt = 0; mt < 2; ++mt)   // A frag: row = lane&15, k = quad*8 + j
        afrag[mt] = *(const bf16x8_t*)(As + (mt * 16 + lrow) * LDK + kk + quad * 8);
#pragma unroll
      for (int mt = 0; mt < 2; ++mt)
#pragma unroll
        for (int nt = 0; nt < 4; ++nt)
          acc[mt][nt] = __builtin_amdgcn_mfma_f32_16x16x32_bf16(afrag[mt], bfrag[nt], acc[mt][nt], 0, 0, 0);
    }
  }

  // C/D layout (m89/m91-verified): row = quad*4 + reg, col = lane&15
#pragma unroll
  for (int mt = 0; mt < 2; ++mt) {
    const int mrow = bm0 + mt * 16 + quad * 4;
#pragma unroll
    for (int nt = 0; nt < 4; ++nt) {
      const int ncol = wn + nt * 16 + lrow;
#pragma unroll
      for (int r = 0; r < 4; ++r)
        C[(size_t)(mrow + r) * NT + ncol] = __float2bfloat16(acc[mt][nt][r]);
    }
  }
}

// ---------------- kernel 2: softmax-compress + RMSNorm + RoPE -------------------------
// 512 threads = 4 row-groups x 128 cols. Each group does an online softmax over 32 of
// the 128 compress positions (unroll 8 -> ~24 loads in flight), then exact flash-merge.
__global__ __launch_bounds__(512)
void k_compress(const __hip_bfloat16* __restrict__ C,      // [MT][NT] bf16
                const void* __restrict__ pbias,            // [128][128]
                const void* __restrict__ nw,               // [128]
                const int* __restrict__ flag,
                void* __restrict__ out) {                  // [128*128]
  const int isF32 = *flag;
  const int tid = threadIdx.x;
  const int j = tid & (DDIM - 1);   // d index 0..127
  const int g = tid >> 7;           // row-group 0..3
  const int bt = blockIdx.x;        // b*64 + t
  const int t  = bt & 63;
  const long i0 = (long)bt * 128;

  // partial online softmax over rows [g*32, g*32+32)
  float mx = -3.0e38f, l = 0.f, acc = 0.f;
#pragma unroll 8
  for (int rr = 0; rr < 32; ++rr) {
    const int r = g * 32 + rr;
    const __hip_bfloat16* row = C + (i0 + r) * NT;
    float pb = isF32 ? ((const float*)pbias)[r * DDIM + j]
                     : __bfloat162float(((const __hip_bfloat16*)pbias)[r * DDIM + j]);
    float gt = __bfloat162float(row[DDIM + j]) + pb;
    float v  = __bfloat162float(row[j]);
    float nm = fmaxf(mx, gt);
    float sc = __expf(mx - nm);
    float e  = __expf(gt - nm);
    l   = l * sc + e;
    acc = acc * sc + e * v;
    mx  = nm;
  }

  __shared__ float smx[4][DDIM], sl[4][DDIM], sa[4][DDIM];
  __shared__ float sh[DDIM];
  __shared__ float ssum[2];
  smx[g][j] = mx; sl[g][j] = l; sa[g][j] = acc;
  __syncthreads();

  float comp = 0.f;
  if (g == 0) {
    // exact merge of 4 partial (m, l, acc) triples
    float M = fmaxf(fmaxf(smx[0][j], smx[1][j]), fmaxf(smx[2][j], smx[3][j]));
    float L = 0.f, A = 0.f;
#pragma unroll
    for (int q = 0; q < 4; ++q) {
      float s = __expf(smx[q][j] - M);
      L += sl[q][j] * s;
      A += sa[q][j] * s;
    }
    comp = A / L;
    // RMS reduce across 128 columns (2 waves)
    float sq = comp * comp;
#pragma unroll
    for (int off = 32; off > 0; off >>= 1) sq += __shfl_down(sq, off, 64);
    if ((j & 63) == 0) ssum[j >> 6] = sq;
  }
  __syncthreads();

  if (g == 0) {
    float var = (ssum[0] + ssum[1]) * (1.0f / DDIM);
    float wv = isF32 ? ((const float*)nw)[j] : __bfloat162float(((const __hip_bfloat16*)nw)[j]);
    float y = comp * rsqrtf(var + 1e-6f) * wv;
    sh[j] = y;
  }
  __syncthreads();

  if (g == 0) {
    float y = sh[j];
    float outv = y;  // nope part (j < 64)
    if (j >= 64) {
      int jj = j - 64;             // rope index 0..63
      int fi = jj >> 1;            // repeat(cos,2): freq index
      double invf = exp((double)fi * (-0.28782313662425575));  // 10000^(-fi/32)
      double ang  = (double)(t * 128) * invf;
      float c = (float)cos(ang);
      float s = (float)sin(ang);
      float other = (jj < 32) ? -sh[64 + jj + 32] : sh[64 + jj - 32];  // rotate_half
      outv = y * c + other * s;
    }
    if (isF32) ((float*)out)[bt * DDIM + j] = outv;
    else       ((__hip_bfloat16*)out)[bt * DDIM + j] = __float2bfloat16(outv);
  }
}

// ---------------- host ----------------------------------------------------------------
extern "C" void kernel_launch(void* const* d_in, const int* in_sizes, int n_in,
                              void* d_out, int out_size, void* d_ws, size_t ws_size,
                              hipStream_t stream) {
  const void* hidden = d_in[0];
  // d_in[1] q_residual, d_in[2] position_ids: unused by the reference
  const void* w_kv   = d_in[3];
  const void* w_gate = d_in[4];
  const void* pbias  = d_in[5];
  const void* nw     = d_in[6];

  // ws layout: [0] flag (int), [256 B) Wt bf16 1 MiB, [256 B + 1 MiB) C bf16 8 MiB
  int* flag = (int*)d_ws;
  __hip_bfloat16* Wt = (__hip_bfloat16*)((char*)d_ws + 256);
  __hip_bfloat16* C  = (__hip_bfloat16*)((char*)d_ws + 256 + (size_t)NT * HDIM * sizeof(__hip_bfloat16));

  k_prep<<<dim3(HDIM / 64, DDIM / 64, 2), 256, 0, stream>>>(w_kv, w_gate,
                                                            (const unsigned short*)hidden, flag, Wt);
  k_gemm<<<dim3(MT / BM), 256, 0, stream>>>(hidden, Wt, flag, C);
  k_compress<<<dim3(128), 512, 0, stream>>>(C, pbias, nw, flag, d_out);
}

// Round 2
// 309.440 us; speedup vs baseline: 1.0986x; 1.0407x over previous
//
#include <hip/hip_runtime.h>
#include <hip/hip_bf16.h>

#define HDIM 2048
#define DDIM 128
#define NT 256        // C cols: kv (0..127) | gate (128..255)
#define BM 32         // rows per block
#define BN 128        // cols per block (N split in 2)
#define BK 64
#define LDA 72        // As leading dim in elements (144 B rows, 16B-aligned, conflict-optimal)
#define MT 16384      // B*S rows

typedef __attribute__((ext_vector_type(8))) short bf16x8_t;
typedef __attribute__((ext_vector_type(4))) float f32x4_t;

// async global->LDS, 16 B per lane. LDS dest is wave-uniform base + lane*16 (HW rule).
#define GLOAD_LDS16(gp, lp)                                                                        \
  __builtin_amdgcn_global_load_lds((const __attribute__((address_space(1))) unsigned int*)(gp),    \
                                   (__attribute__((address_space(3))) unsigned int*)(lp), 16, 0, 0)

// ---------------- kernel 0: detect dtype (inline) + transpose/convert weights --------
// fp32 data viewed as u16: low halves have uniform-random "exponent" bits -> huge bf16s.
// genuine bf16 N(0,1) data never has exponent >= 167 (|x| > 2^40).
__global__ void k_prep(const void* __restrict__ w_kv, const void* __restrict__ w_gate,
                       const unsigned short* __restrict__ hidden,
                       int* __restrict__ flag, __hip_bfloat16* __restrict__ Wt) {
  __shared__ int sflag;
  __shared__ float tile[64][65];
  int bad = 0;
  for (int i = threadIdx.x; i < 8192; i += 256)
    bad |= (((hidden[i] >> 7) & 0xFF) >= 167) ? 1 : 0;
  if (threadIdx.x == 0) sflag = 0;
  __syncthreads();
  if (bad) atomicOr(&sflag, 1);
  __syncthreads();
  const int isF32 = sflag;
  if (threadIdx.x == 0 && blockIdx.x == 0 && blockIdx.y == 0 && blockIdx.z == 0)
    *flag = isF32;   // publish for k_gemm / k_compress (stream-ordered)

  const void* src = blockIdx.z ? w_gate : w_kv;
  const int k0 = blockIdx.x * 64;
  const int n0 = blockIdx.y * 64;
  const int tx = threadIdx.x & 63;
  const int ty = threadIdx.x >> 6;  // 0..3
#pragma unroll
  for (int i = 0; i < 16; ++i) {
    int r = i * 4 + ty;
    int idx = (k0 + r) * DDIM + n0 + tx;
    float v = isF32 ? ((const float*)src)[idx]
                    : __bfloat162float(((const __hip_bfloat16*)src)[idx]);
    tile[tx][r] = v;
  }
  __syncthreads();
#pragma unroll
  for (int i = 0; i < 16; ++i) {
    int r = i * 4 + ty;
    Wt[(blockIdx.z * DDIM + n0 + r) * HDIM + k0 + tx] = __float2bfloat16(tile[r][tx]);
  }
}

// ---------------- kernel 1: C[16384][256] = hidden @ [w_kv | w_gate] (bf16 MFMA) ------
// 32(m) x 128(n) block tile, 4 waves each 32x32. Grid 1024 = 4 blocks/CU.
// B panel staged LDS via global_load_lds (16B, XOR-swizzled source; swizzled ds_read).
// A staged via register prefetch + fp32->bf16 convert -> LDS.
__global__ __launch_bounds__(256, 4)
void k_gemm(const void* __restrict__ hidden, const __hip_bfloat16* __restrict__ Wt,
            const int* __restrict__ flag, __hip_bfloat16* __restrict__ C) {
  __shared__ __align__(1024) __hip_bfloat16 Bs[BN * BK];   // 16 KB, swizzled [n][k]
  __shared__ __align__(16)   __hip_bfloat16 As[BM * LDA];  // 4.6 KB
  const int isF32 = *flag;
  const int tid  = threadIdx.x;
  const int w    = tid >> 6;
  const int lane = tid & 63;
  const int lrow = lane & 15;
  const int quad = lane >> 4;

  // bijective XCD swizzle (1024 = 8*128): hw block bw -> logical L with xcd(L) = L/128,
  // so logical pairs (band, half0/half1) land on the SAME XCD, 8 dispatch slots apart.
  const int bw  = blockIdx.x;
  const int L   = ((bw & 7) << 7) + (bw >> 3);
  const int bm0 = (L >> 1) * BM;
  const int n0  = (L & 1) * BN;

  f32x4_t acc[2][2];
#pragma unroll
  for (int i = 0; i < 2; ++i)
#pragma unroll
    for (int j = 0; j < 2; ++j) acc[i][j] = (f32x4_t){0.f, 0.f, 0.f, 0.f};

  // ---- A staging role: row = tid>>3 (0..31), k-seg = (tid&7)*8 (8 elems = 16B bf16)
  const int srow = tid >> 3;
  const int skg  = (tid & 7) * 8;
  const float*          Af = (const float*)hidden + (size_t)(bm0 + srow) * HDIM + skg;
  const unsigned short* Ab = (const unsigned short*)hidden + (size_t)(bm0 + srow) * HDIM + skg;

  // ---- B staging role: per wave 32 rows (4 calls x 8 rows), linear LDS dest,
  // global source pre-swizzled: klog_byte = ((lane&7)*16) ^ ((lane>>3)<<4)
  const int soff = (((lane & 7) ^ (lane >> 3)) << 4);
  const char* WtB = (const char*)Wt;
  const char* bsrc0 = WtB + (size_t)(n0 + w * 32 + 0 * 8 + (lane >> 3)) * (HDIM * 2) + soff;
  const char* bsrc1 = WtB + (size_t)(n0 + w * 32 + 1 * 8 + (lane >> 3)) * (HDIM * 2) + soff;
  const char* bsrc2 = WtB + (size_t)(n0 + w * 32 + 2 * 8 + (lane >> 3)) * (HDIM * 2) + soff;
  const char* bsrc3 = WtB + (size_t)(n0 + w * 32 + 3 * 8 + (lane >> 3)) * (HDIM * 2) + soff;
  char* ldst0 = (char*)Bs + w * 4096 + 0 * 1024;
  char* ldst1 = (char*)Bs + w * 4096 + 1 * 1024;
  char* ldst2 = (char*)Bs + w * 4096 + 2 * 1024;
  char* ldst3 = (char*)Bs + w * 4096 + 3 * 1024;

  float4 pa0, pa1;  // fp32-path A prefetch (8 f32 = 32 B)
  int4   pb;        // bf16-path A prefetch (8 bf16 = 16 B)
  if (isF32) { pa0 = *(const float4*)(Af); pa1 = *(const float4*)(Af + 4); }
  else       { pb = *(const int4*)(Ab); }

  for (int k0 = 0; k0 < HDIM; k0 += BK) {
    __syncthreads();  // previous iteration's LDS reads complete
    // A: registers -> LDS (one 16B write per thread)
    if (isF32) {
      union { int4 v; __hip_bfloat16 h[8]; } u;
      u.h[0] = __float2bfloat16(pa0.x); u.h[1] = __float2bfloat16(pa0.y);
      u.h[2] = __float2bfloat16(pa0.z); u.h[3] = __float2bfloat16(pa0.w);
      u.h[4] = __float2bfloat16(pa1.x); u.h[5] = __float2bfloat16(pa1.y);
      u.h[6] = __float2bfloat16(pa1.z); u.h[7] = __float2bfloat16(pa1.w);
      *(int4*)(As + srow * LDA + skg) = u.v;
    } else {
      *(int4*)(As + srow * LDA + skg) = pb;
    }
    // B: async global -> LDS (this iteration's panel slice), no VGPR round-trip
    GLOAD_LDS16(bsrc0 + 2 * k0, ldst0);
    GLOAD_LDS16(bsrc1 + 2 * k0, ldst1);
    GLOAD_LDS16(bsrc2 + 2 * k0, ldst2);
    GLOAD_LDS16(bsrc3 + 2 * k0, ldst3);
    // A: prefetch next K tile into registers
    if (k0 + BK < HDIM) {
      if (isF32) { pa0 = *(const float4*)(Af + k0 + BK); pa1 = *(const float4*)(Af + k0 + BK + 4); }
      else       { pb = *(const int4*)(Ab + k0 + BK); }
    }
    __syncthreads();  // compiler emits vmcnt(0): A visible, B landed in LDS

#pragma unroll
    for (int kk = 0; kk < 2; ++kk) {
      bf16x8_t af0 = *(const bf16x8_t*)(As + (0 * 16 + lrow) * LDA + kk * 32 + quad * 8);
      bf16x8_t af1 = *(const bf16x8_t*)(As + (1 * 16 + lrow) * LDA + kk * 32 + quad * 8);
      const int rl0 = ((kk * 64 + quad * 16) ^ ((lrow & 7) << 4));
      bf16x8_t bf0 = *(const bf16x8_t*)((const char*)Bs + (w * 32 + 0 * 16 + lrow) * 128 + rl0);
      bf16x8_t bf1 = *(const bf16x8_t*)((const char*)Bs + (w * 32 + 1 * 16 + lrow) * 128 + rl0);
      acc[0][0] = __builtin_amdgcn_mfma_f32_16x16x32_bf16(af0, bf0, acc[0][0], 0, 0, 0);
      acc[0][1] = __builtin_amdgcn_mfma_f32_16x16x32_bf16(af0, bf1, acc[0][1], 0, 0, 0);
      acc[1][0] = __builtin_amdgcn_mfma_f32_16x16x32_bf16(af1, bf0, acc[1][0], 0, 0, 0);
      acc[1][1] = __builtin_amdgcn_mfma_f32_16x16x32_bf16(af1, bf1, acc[1][1], 0, 0, 0);
    }
  }

  // C/D layout (m89/m91-verified): row = quad*4 + reg, col = lane&15
#pragma unroll
  for (int mt = 0; mt < 2; ++mt) {
    const int mrow = bm0 + mt * 16 + quad * 4;
#pragma unroll
    for (int nt = 0; nt < 2; ++nt) {
      const int ncol = n0 + w * 32 + nt * 16 + lrow;
#pragma unroll
      for (int r = 0; r < 4; ++r)
        C[(size_t)(mrow + r) * NT + ncol] = __float2bfloat16(acc[mt][nt][r]);
    }
  }
}

// ---------------- kernel 2: softmax-compress + RMSNorm + RoPE -------------------------
// 512 threads = 4 row-groups x 128 cols; flash-style exact merge of partial softmaxes.
__global__ __launch_bounds__(512)
void k_compress(const __hip_bfloat16* __restrict__ C,      // [MT][NT] bf16
                const void* __restrict__ pbias,            // [128][128]
                const void* __restrict__ nw,               // [128]
                const int* __restrict__ flag,
                void* __restrict__ out) {                  // [128*128]
  const int isF32 = *flag;
  const int tid = threadIdx.x;
  const int j = tid & (DDIM - 1);   // d index 0..127
  const int g = tid >> 7;           // row-group 0..3
  const int bt = blockIdx.x;        // b*64 + t
  const int t  = bt & 63;
  const long i0 = (long)bt * 128;

  float mx = -3.0e38f, l = 0.f, acc = 0.f;
#pragma unroll 8
  for (int rr = 0; rr < 32; ++rr) {
    const int r = g * 32 + rr;
    const __hip_bfloat16* row = C + (i0 + r) * NT;
    float pb = isF32 ? ((const float*)pbias)[r * DDIM + j]
                     : __bfloat162float(((const __hip_bfloat16*)pbias)[r * DDIM + j]);
    float gt = __bfloat162float(row[DDIM + j]) + pb;
    float v  = __bfloat162float(row[j]);
    float nm = fmaxf(mx, gt);
    float sc = __expf(mx - nm);
    float e  = __expf(gt - nm);
    l   = l * sc + e;
    acc = acc * sc + e * v;
    mx  = nm;
  }

  __shared__ float smx[4][DDIM], sl[4][DDIM], sa[4][DDIM];
  __shared__ float sh[DDIM];
  __shared__ float ssum[2];
  smx[g][j] = mx; sl[g][j] = l; sa[g][j] = acc;
  __syncthreads();

  float comp = 0.f;
  if (g == 0) {
    float M = fmaxf(fmaxf(smx[0][j], smx[1][j]), fmaxf(smx[2][j], smx[3][j]));
    float L = 0.f, A = 0.f;
#pragma unroll
    for (int q = 0; q < 4; ++q) {
      float s = __expf(smx[q][j] - M);
      L += sl[q][j] * s;
      A += sa[q][j] * s;
    }
    comp = A / L;
    float sq = comp * comp;
#pragma unroll
    for (int off = 32; off > 0; off >>= 1) sq += __shfl_down(sq, off, 64);
    if ((j & 63) == 0) ssum[j >> 6] = sq;
  }
  __syncthreads();

  if (g == 0) {
    float var = (ssum[0] + ssum[1]) * (1.0f / DDIM);
    float wv = isF32 ? ((const float*)nw)[j] : __bfloat162float(((const __hip_bfloat16*)nw)[j]);
    float y = comp * rsqrtf(var + 1e-6f) * wv;
    sh[j] = y;
  }
  __syncthreads();

  if (g == 0) {
    float y = sh[j];
    float outv = y;  // nope part (j < 64)
    if (j >= 64) {
      int jj = j - 64;             // rope index 0..63
      int fi = jj >> 1;            // repeat(cos,2): freq index
      double invf = exp((double)fi * (-0.28782313662425575));  // 10000^(-fi/32)
      double ang  = (double)(t * 128) * invf;
      float c = (float)cos(ang);
      float s = (float)sin(ang);
      float other = (jj < 32) ? -sh[64 + jj + 32] : sh[64 + jj - 32];  // rotate_half
      outv = y * c + other * s;
    }
    if (isF32) ((float*)out)[bt * DDIM + j] = outv;
    else       ((__hip_bfloat16*)out)[bt * DDIM + j] = __float2bfloat16(outv);
  }
}

// ---------------- host ----------------------------------------------------------------
extern "C" void kernel_launch(void* const* d_in, const int* in_sizes, int n_in,
                              void* d_out, int out_size, void* d_ws, size_t ws_size,
                              hipStream_t stream) {
  const void* hidden = d_in[0];
  // d_in[1] q_residual, d_in[2] position_ids: unused by the reference
  const void* w_kv   = d_in[3];
  const void* w_gate = d_in[4];
  const void* pbias  = d_in[5];
  const void* nw     = d_in[6];

  // ws layout: [0] flag (int), [256 B) Wt bf16 1 MiB, [256 B + 1 MiB) C bf16 8 MiB
  int* flag = (int*)d_ws;
  __hip_bfloat16* Wt = (__hip_bfloat16*)((char*)d_ws + 256);
  __hip_bfloat16* C  = (__hip_bfloat16*)((char*)d_ws + 256 + (size_t)NT * HDIM * sizeof(__hip_bfloat16));

  k_prep<<<dim3(HDIM / 64, DDIM / 64, 2), 256, 0, stream>>>(w_kv, w_gate,
                                                            (const unsigned short*)hidden, flag, Wt);
  k_gemm<<<dim3((MT / BM) * 2), 256, 0, stream>>>(hidden, Wt, flag, C);
  k_compress<<<dim3(128), 512, 0, stream>>>(C, pbias, nw, flag, d_out);
}

// Round 3
// 302.300 us; speedup vs baseline: 1.1246x; 1.0236x over previous
//
#include <hip/hip_runtime.h>
#include <hip/hip_bf16.h>

#define HDIM 2048
#define DDIM 128
#define NT 256        // C cols: kv (0..127) | gate (128..255)
#define BM 32         // rows per block
#define BN 128        // cols per block (N split in 2)
#define BK 64
#define MT 16384      // B*S rows
#define BSB 16384     // Bs buffer bytes (BN*BK*2)
#define ASB 4096      // As buffer bytes (BM*BK*2)

typedef __attribute__((ext_vector_type(8))) short bf16x8_t;
typedef __attribute__((ext_vector_type(4))) float f32x4_t;

// async global->LDS, 16 B per lane. LDS dest is wave-uniform base + lane*16 (HW rule).
#define GLOAD_LDS16(gp, lp)                                                                        \
  __builtin_amdgcn_global_load_lds((const __attribute__((address_space(1))) unsigned int*)(gp),    \
                                   (__attribute__((address_space(3))) unsigned int*)(lp), 16, 0, 0)

// ---------------- kernel 0: detect dtype (inline) + transpose/convert weights --------
// fp32 data viewed as u16: low halves have uniform-random "exponent" bits -> huge bf16s.
// genuine bf16 N(0,1) data never has exponent >= 167 (|x| > 2^40).
__global__ void k_prep(const void* __restrict__ w_kv, const void* __restrict__ w_gate,
                       const unsigned short* __restrict__ hidden,
                       int* __restrict__ flag, __hip_bfloat16* __restrict__ Wt) {
  __shared__ int sflag;
  __shared__ float tile[64][65];
  int bad = 0;
  for (int i = threadIdx.x; i < 8192; i += 256)
    bad |= (((hidden[i] >> 7) & 0xFF) >= 167) ? 1 : 0;
  if (threadIdx.x == 0) sflag = 0;
  __syncthreads();
  if (bad) atomicOr(&sflag, 1);
  __syncthreads();
  const int isF32 = sflag;
  if (threadIdx.x == 0 && blockIdx.x == 0 && blockIdx.y == 0 && blockIdx.z == 0)
    *flag = isF32;   // publish for k_gemm / k_compress (stream-ordered)

  const void* src = blockIdx.z ? w_gate : w_kv;
  const int k0 = blockIdx.x * 64;
  const int n0 = blockIdx.y * 64;
  const int tx = threadIdx.x & 63;
  const int ty = threadIdx.x >> 6;  // 0..3
#pragma unroll
  for (int i = 0; i < 16; ++i) {
    int r = i * 4 + ty;
    int idx = (k0 + r) * DDIM + n0 + tx;
    float v = isF32 ? ((const float*)src)[idx]
                    : __bfloat162float(((const __hip_bfloat16*)src)[idx]);
    tile[tx][r] = v;
  }
  __syncthreads();
#pragma unroll
  for (int i = 0; i < 16; ++i) {
    int r = i * 4 + ty;
    Wt[(blockIdx.z * DDIM + n0 + r) * HDIM + k0 + tx] = __float2bfloat16(tile[r][tx]);
  }
}

// ---------------- kernel 1: C[16384][256] = hidden @ [w_kv | w_gate] (bf16 MFMA) ------
// 32(m) x 128(n) block tile, 4 waves each 32x32. Grid 1024 = 4 blocks/CU.
// 2-phase double-buffered pipeline (T3 minimum recipe): issue tile t+1 loads BEFORE
// computing tile t; single vmcnt(0)+barrier per iteration finds loads already landed.
// B panel: global_load_lds 16B, XOR-swizzled source, linear LDS dest (G21 pattern).
// A panel: global->reg prefetch + fp32->bf16 convert -> XOR-swizzled LDS write.
__global__ __launch_bounds__(256, 4)
void k_gemm(const void* __restrict__ hidden, const __hip_bfloat16* __restrict__ Wt,
            const int* __restrict__ flag, __hip_bfloat16* __restrict__ C) {
  __shared__ __align__(1024) __hip_bfloat16 Bs[2 * BN * BK];   // 32 KB, swizzled [n][k]
  __shared__ __align__(1024) __hip_bfloat16 As[2 * BM * BK];   // 8 KB, swizzled [m][k]
  const int isF32 = *flag;
  const int tid  = threadIdx.x;
  const int w    = tid >> 6;
  const int lane = tid & 63;
  const int lrow = lane & 15;
  const int quad = lane >> 4;

  // bijective XCD swizzle (1024 = 8*128): logical pairs (band, half0/half1) land on
  // the SAME XCD, 8 dispatch slots apart -> A-band re-read is L2-local.
  const int bw  = blockIdx.x;
  const int L   = ((bw & 7) << 7) + (bw >> 3);
  const int bm0 = (L >> 1) * BM;
  const int n0  = (L & 1) * BN;

  f32x4_t acc[2][2];
#pragma unroll
  for (int i = 0; i < 2; ++i)
#pragma unroll
    for (int j = 0; j < 2; ++j) acc[i][j] = (f32x4_t){0.f, 0.f, 0.f, 0.f};

  // ---- A staging role: row = tid>>3 (0..31), k-seg bytes = (tid&7)*16
  const int srow = tid >> 3;
  const int skb  = (tid & 7) * 16;                       // byte col within 128 B row
  const int awoff = srow * 128 + (skb ^ ((srow & 7) << 4));  // swizzled write offset
  const float*          Af = (const float*)hidden + (size_t)(bm0 + srow) * HDIM + (tid & 7) * 8;
  const unsigned short* Ab = (const unsigned short*)hidden + (size_t)(bm0 + srow) * HDIM + (tid & 7) * 8;

  // ---- B staging role: per wave 32 rows (4 calls x 8 rows), linear LDS dest,
  // global source pre-swizzled: kbyte = ((lane&7)*16) ^ ((lane>>3)<<4)
  const int soff = (((lane & 7) ^ (lane >> 3)) << 4);
  const char* WtB = (const char*)Wt;
  const char* bsrc0 = WtB + (size_t)(n0 + w * 32 + 0 * 8 + (lane >> 3)) * (HDIM * 2) + soff;
  const char* bsrc1 = WtB + (size_t)(n0 + w * 32 + 1 * 8 + (lane >> 3)) * (HDIM * 2) + soff;
  const char* bsrc2 = WtB + (size_t)(n0 + w * 32 + 2 * 8 + (lane >> 3)) * (HDIM * 2) + soff;
  const char* bsrc3 = WtB + (size_t)(n0 + w * 32 + 3 * 8 + (lane >> 3)) * (HDIM * 2) + soff;
  char* const bbase = (char*)Bs;
  char* const abase = (char*)As;

  float4 pa0, pa1;  // fp32-path A prefetch (8 f32 = 32 B)
  int4   pb;        // bf16-path A prefetch (8 bf16 = 16 B)

  // ---- prologue: stage tile 0 into buffer 0
  if (isF32) { pa0 = *(const float4*)(Af); pa1 = *(const float4*)(Af + 4); }
  else       { pb = *(const int4*)(Ab); }
  {
    char* bd = bbase + w * 4096;
    GLOAD_LDS16(bsrc0, bd + 0 * 1024);
    GLOAD_LDS16(bsrc1, bd + 1 * 1024);
    GLOAD_LDS16(bsrc2, bd + 2 * 1024);
    GLOAD_LDS16(bsrc3, bd + 3 * 1024);
  }
  if (isF32) {
    union { int4 v; __hip_bfloat16 h[8]; } u;
    u.h[0] = __float2bfloat16(pa0.x); u.h[1] = __float2bfloat16(pa0.y);
    u.h[2] = __float2bfloat16(pa0.z); u.h[3] = __float2bfloat16(pa0.w);
    u.h[4] = __float2bfloat16(pa1.x); u.h[5] = __float2bfloat16(pa1.y);
    u.h[6] = __float2bfloat16(pa1.z); u.h[7] = __float2bfloat16(pa1.w);
    *(int4*)(abase + awoff) = u.v;
  } else {
    *(int4*)(abase + awoff) = pb;
  }
  __syncthreads();  // vmcnt(0): B0 landed; As0 visible

  int cur = 0;
  for (int k0 = 0; k0 < HDIM; k0 += BK) {
    const int nk = k0 + BK;
    const int nxt = cur ^ 1;
    if (nk < HDIM) {
      // issue next A into regs FIRST (so its wait is vmcnt(4), not vmcnt(0))
      if (isF32) { pa0 = *(const float4*)(Af + nk); pa1 = *(const float4*)(Af + nk + 4); }
      else       { pb = *(const int4*)(Ab + nk); }
      // issue next B panel slice into the other buffer (flies under the compute below)
      char* bd = bbase + nxt * BSB + w * 4096;
      GLOAD_LDS16(bsrc0 + 2 * nk, bd + 0 * 1024);
      GLOAD_LDS16(bsrc1 + 2 * nk, bd + 1 * 1024);
      GLOAD_LDS16(bsrc2 + 2 * nk, bd + 2 * 1024);
      GLOAD_LDS16(bsrc3 + 2 * nk, bd + 3 * 1024);
    }

    // compute tile t from buffer cur
    const char* ab = abase + cur * ASB;
    const char* bb = bbase + cur * BSB;
#pragma unroll
    for (int kk = 0; kk < 2; ++kk) {
      const int rl = (kk * 64 + quad * 16) ^ ((lrow & 7) << 4);
      bf16x8_t af0 = *(const bf16x8_t*)(ab + (0 * 16 + lrow) * 128 + rl);
      bf16x8_t af1 = *(const bf16x8_t*)(ab + (1 * 16 + lrow) * 128 + rl);
      bf16x8_t bf0 = *(const bf16x8_t*)(bb + (w * 32 + 0 * 16 + lrow) * 128 + rl);
      bf16x8_t bf1 = *(const bf16x8_t*)(bb + (w * 32 + 1 * 16 + lrow) * 128 + rl);
      acc[0][0] = __builtin_amdgcn_mfma_f32_16x16x32_bf16(af0, bf0, acc[0][0], 0, 0, 0);
      acc[0][1] = __builtin_amdgcn_mfma_f32_16x16x32_bf16(af0, bf1, acc[0][1], 0, 0, 0);
      acc[1][0] = __builtin_amdgcn_mfma_f32_16x16x32_bf16(af1, bf0, acc[1][0], 0, 0, 0);
      acc[1][1] = __builtin_amdgcn_mfma_f32_16x16x32_bf16(af1, bf1, acc[1][1], 0, 0, 0);
    }

    if (nk < HDIM) {
      // write next A (regs -> other LDS buffer); compiler waits only the A-reg loads
      if (isF32) {
        union { int4 v; __hip_bfloat16 h[8]; } u;
        u.h[0] = __float2bfloat16(pa0.x); u.h[1] = __float2bfloat16(pa0.y);
        u.h[2] = __float2bfloat16(pa0.z); u.h[3] = __float2bfloat16(pa0.w);
        u.h[4] = __float2bfloat16(pa1.x); u.h[5] = __float2bfloat16(pa1.y);
        u.h[6] = __float2bfloat16(pa1.z); u.h[7] = __float2bfloat16(pa1.w);
        *(int4*)(abase + nxt * ASB + awoff) = u.v;
      } else {
        *(int4*)(abase + nxt * ASB + awoff) = pb;
      }
      __syncthreads();  // vmcnt(0): next B landed (it flew during compute); As visible
      cur = nxt;
    }
  }

  // C/D layout (m89/m91-verified): row = quad*4 + reg, col = lane&15
#pragma unroll
  for (int mt = 0; mt < 2; ++mt) {
    const int mrow = bm0 + mt * 16 + quad * 4;
#pragma unroll
    for (int nt = 0; nt < 2; ++nt) {
      const int ncol = n0 + w * 32 + nt * 16 + lrow;
#pragma unroll
      for (int r = 0; r < 4; ++r)
        C[(size_t)(mrow + r) * NT + ncol] = __float2bfloat16(acc[mt][nt][r]);
    }
  }
}

// ---------------- kernel 2: softmax-compress + RMSNorm + RoPE -------------------------
// 512 threads = 4 row-groups x 128 cols; flash-style exact merge of partial softmaxes.
__global__ __launch_bounds__(512)
void k_compress(const __hip_bfloat16* __restrict__ C,      // [MT][NT] bf16
                const void* __restrict__ pbias,            // [128][128]
                const void* __restrict__ nw,               // [128]
                const int* __restrict__ flag,
                void* __restrict__ out) {                  // [128*128]
  const int isF32 = *flag;
  const int tid = threadIdx.x;
  const int j = tid & (DDIM - 1);   // d index 0..127
  const int g = tid >> 7;           // row-group 0..3
  const int bt = blockIdx.x;        // b*64 + t
  const int t  = bt & 63;
  const long i0 = (long)bt * 128;

  float mx = -3.0e38f, l = 0.f, acc = 0.f;
#pragma unroll 8
  for (int rr = 0; rr < 32; ++rr) {
    const int r = g * 32 + rr;
    const __hip_bfloat16* row = C + (i0 + r) * NT;
    float pb = isF32 ? ((const float*)pbias)[r * DDIM + j]
                     : __bfloat162float(((const __hip_bfloat16*)pbias)[r * DDIM + j]);
    float gt = __bfloat162float(row[DDIM + j]) + pb;
    float v  = __bfloat162float(row[j]);
    float nm = fmaxf(mx, gt);
    float sc = __expf(mx - nm);
    float e  = __expf(gt - nm);
    l   = l * sc + e;
    acc = acc * sc + e * v;
    mx  = nm;
  }

  __shared__ float smx[4][DDIM], sl[4][DDIM], sa[4][DDIM];
  __shared__ float sh[DDIM];
  __shared__ float ssum[2];
  smx[g][j] = mx; sl[g][j] = l; sa[g][j] = acc;
  __syncthreads();

  float comp = 0.f;
  if (g == 0) {
    float M = fmaxf(fmaxf(smx[0][j], smx[1][j]), fmaxf(smx[2][j], smx[3][j]));
    float L = 0.f, A = 0.f;
#pragma unroll
    for (int q = 0; q < 4; ++q) {
      float s = __expf(smx[q][j] - M);
      L += sl[q][j] * s;
      A += sa[q][j] * s;
    }
    comp = A / L;
    float sq = comp * comp;
#pragma unroll
    for (int off = 32; off > 0; off >>= 1) sq += __shfl_down(sq, off, 64);
    if ((j & 63) == 0) ssum[j >> 6] = sq;
  }
  __syncthreads();

  if (g == 0) {
    float var = (ssum[0] + ssum[1]) * (1.0f / DDIM);
    float wv = isF32 ? ((const float*)nw)[j] : __bfloat162float(((const __hip_bfloat16*)nw)[j]);
    float y = comp * rsqrtf(var + 1e-6f) * wv;
    sh[j] = y;
  }
  __syncthreads();

  if (g == 0) {
    float y = sh[j];
    float outv = y;  // nope part (j < 64)
    if (j >= 64) {
      int jj = j - 64;             // rope index 0..63
      int fi = jj >> 1;            // repeat(cos,2): freq index
      double invf = exp((double)fi * (-0.28782313662425575));  // 10000^(-fi/32)
      double ang  = (double)(t * 128) * invf;
      float c = (float)cos(ang);
      float s = (float)sin(ang);
      float other = (jj < 32) ? -sh[64 + jj + 32] : sh[64 + jj - 32];  // rotate_half
      outv = y * c + other * s;
    }
    if (isF32) ((float*)out)[bt * DDIM + j] = outv;
    else       ((__hip_bfloat16*)out)[bt * DDIM + j] = __float2bfloat16(outv);
  }
}

// ---------------- host ----------------------------------------------------------------
extern "C" void kernel_launch(void* const* d_in, const int* in_sizes, int n_in,
                              void* d_out, int out_size, void* d_ws, size_t ws_size,
                              hipStream_t stream) {
  const void* hidden = d_in[0];
  // d_in[1] q_residual, d_in[2] position_ids: unused by the reference
  const void* w_kv   = d_in[3];
  const void* w_gate = d_in[4];
  const void* pbias  = d_in[5];
  const void* nw     = d_in[6];

  // ws layout: [0] flag (int), [256 B) Wt bf16 1 MiB, [256 B + 1 MiB) C bf16 8 MiB
  int* flag = (int*)d_ws;
  __hip_bfloat16* Wt = (__hip_bfloat16*)((char*)d_ws + 256);
  __hip_bfloat16* C  = (__hip_bfloat16*)((char*)d_ws + 256 + (size_t)NT * HDIM * sizeof(__hip_bfloat16));

  k_prep<<<dim3(HDIM / 64, DDIM / 64, 2), 256, 0, stream>>>(w_kv, w_gate,
                                                            (const unsigned short*)hidden, flag, Wt);
  k_gemm<<<dim3((MT / BM) * 2), 256, 0, stream>>>(hidden, Wt, flag, C);
  k_compress<<<dim3(128), 512, 0, stream>>>(C, pbias, nw, flag, d_out);
}

// Round 4
// 288.727 us; speedup vs baseline: 1.1775x; 1.0470x over previous
//
#include <hip/hip_runtime.h>
#include <hip/hip_bf16.h>

#define HDIM 2048
#define DDIM 128
#define NT 256        // C cols: kv (0..127) | gate (128..255)
#define BM 32         // rows per block
#define BN 256        // cols per block = full N (no A re-read)
#define BK 64
#define MT 16384      // B*S rows
#define BSB 32768     // Bs buffer bytes (BN*BK*2)
#define ASB 4096      // As buffer bytes (BM*BK*2)

typedef __attribute__((ext_vector_type(8))) short bf16x8_t;
typedef __attribute__((ext_vector_type(4))) float f32x4_t;

// async global->LDS, 16 B per lane. LDS dest is wave-uniform base + lane*16 (HW rule).
#define GLOAD_LDS16(gp, lp)                                                                        \
  __builtin_amdgcn_global_load_lds((const __attribute__((address_space(1))) unsigned int*)(gp),    \
                                   (__attribute__((address_space(3))) unsigned int*)(lp), 16, 0, 0)

// ---------------- kernel 0: detect dtype (inline) + transpose/convert weights --------
// fp32 data viewed as u16: low halves have uniform-random "exponent" bits -> huge bf16s.
// genuine bf16 N(0,1) data never has exponent >= 167 (|x| > 2^40).
__global__ void k_prep(const void* __restrict__ w_kv, const void* __restrict__ w_gate,
                       const unsigned short* __restrict__ hidden,
                       int* __restrict__ flag, __hip_bfloat16* __restrict__ Wt) {
  __shared__ int sflag;
  __shared__ float tile[64][65];
  int bad = 0;
  for (int i = threadIdx.x; i < 8192; i += 256)
    bad |= (((hidden[i] >> 7) & 0xFF) >= 167) ? 1 : 0;
  if (threadIdx.x == 0) sflag = 0;
  __syncthreads();
  if (bad) atomicOr(&sflag, 1);
  __syncthreads();
  const int isF32 = sflag;
  if (threadIdx.x == 0 && blockIdx.x == 0 && blockIdx.y == 0 && blockIdx.z == 0)
    *flag = isF32;   // publish for k_gemm / k_compress (stream-ordered)

  const void* src = blockIdx.z ? w_gate : w_kv;
  const int k0 = blockIdx.x * 64;
  const int n0 = blockIdx.y * 64;
  const int tx = threadIdx.x & 63;
  const int ty = threadIdx.x >> 6;  // 0..3
#pragma unroll
  for (int i = 0; i < 16; ++i) {
    int r = i * 4 + ty;
    int idx = (k0 + r) * DDIM + n0 + tx;
    float v = isF32 ? ((const float*)src)[idx]
                    : __bfloat162float(((const __hip_bfloat16*)src)[idx]);
    tile[tx][r] = v;
  }
  __syncthreads();
#pragma unroll
  for (int i = 0; i < 16; ++i) {
    int r = i * 4 + ty;
    Wt[(blockIdx.z * DDIM + n0 + r) * HDIM + k0 + tx] = __float2bfloat16(tile[r][tx]);
  }
}

// ---------------- kernel 1: C[16384][256] = hidden @ [w_kv | w_gate] (bf16 MFMA) ------
// 32(m) x 256(n) block, 8 waves each 32x32. Grid 512 = 2 blocks/CU (LDS 72 KB).
// T4 counted-vmcnt pipeline: raw s_barrier (NO vmcnt drain); t+1's loads stay in
// flight across the barrier. Each wave self-stages its own 32 B-rows via
// global_load_lds -> per-wave vmcnt ordering; no barrier needed for B at all.
// The single barrier per iter covers only the cross-wave As tile (lgkmcnt(0) only).
__global__ __launch_bounds__(512, 4)
void k_gemm(const void* __restrict__ hidden, const __hip_bfloat16* __restrict__ Wt,
            const int* __restrict__ flag, __hip_bfloat16* __restrict__ C) {
  __shared__ __align__(1024) __hip_bfloat16 Bs[2 * BN * BK];   // 64 KB, swizzled [n][k]
  __shared__ __align__(1024) __hip_bfloat16 As[2 * BM * BK];   // 8 KB, swizzled [m][k]
  const int isF32 = *flag;
  const int tid  = threadIdx.x;
  const int w    = tid >> 6;         // wave 0..7, owns output cols [w*32, w*32+32)
  const int lane = tid & 63;
  const int lrow = lane & 15;
  const int quad = lane >> 4;
  const int bw   = blockIdx.x;
  const int bm0  = bw * BM;
  const int phase = bw & 31;         // K-phase stagger (sum order-independent)

  f32x4_t acc[2][2];
#pragma unroll
  for (int i = 0; i < 2; ++i)
#pragma unroll
    for (int j = 0; j < 2; ++j) acc[i][j] = (f32x4_t){0.f, 0.f, 0.f, 0.f};

  // ---- A staging (tid<256 only): row = tid>>3 (0..31), 16B unit = tid&7
  const int srow  = tid >> 3;
  const int awoff = srow * 128 + (((tid & 7) * 16) ^ ((srow & 7) << 4));  // proven 0-conflict
  const float*          Af = (const float*)hidden + (size_t)(bm0 + srow) * HDIM + (tid & 7) * 8;
  const unsigned short* Ab = (const unsigned short*)hidden + (size_t)(bm0 + srow) * HDIM + (tid & 7) * 8;

  // ---- B staging: wave w stages rows [w*32, w*32+32) (4 instrs x 8 rows), linear LDS
  // dest, global source pre-swizzled: kbyte = ((lane&7)*16) ^ ((lane>>3)<<4)
  const int soff = (((lane & 7) ^ (lane >> 3)) << 4);
  const char* WtB = (const char*)Wt;
  const char* bsrc0 = WtB + (size_t)(w * 32 + 0 * 8 + (lane >> 3)) * (HDIM * 2) + soff;
  const char* bsrc1 = WtB + (size_t)(w * 32 + 1 * 8 + (lane >> 3)) * (HDIM * 2) + soff;
  const char* bsrc2 = WtB + (size_t)(w * 32 + 2 * 8 + (lane >> 3)) * (HDIM * 2) + soff;
  const char* bsrc3 = WtB + (size_t)(w * 32 + 3 * 8 + (lane >> 3)) * (HDIM * 2) + soff;

  float4 pa0, pa1;   // fp32-path A prefetch (2 instrs)
  int2   qb0, qb1;   // bf16-path A prefetch (2 instrs -> same vmcnt math)

#define ISSUE_A(kk)                                                                     \
  do { if (tid < 256) {                                                                 \
    if (isF32) { pa0 = *(const float4*)(Af + (kk)); pa1 = *(const float4*)(Af + (kk) + 4); } \
    else       { qb0 = *(const int2*)(Ab + (kk));   qb1 = *(const int2*)(Ab + (kk) + 4); } \
  } } while (0)

#define STAGE_B(kb, bufbase)                                                            \
  do {                                                                                  \
    char* bd = (char*)Bs + (bufbase) + w * 4096;                                        \
    GLOAD_LDS16(bsrc0 + (kb), bd + 0 * 1024);                                           \
    GLOAD_LDS16(bsrc1 + (kb), bd + 1 * 1024);                                           \
    GLOAD_LDS16(bsrc2 + (kb), bd + 2 * 1024);                                           \
    GLOAD_LDS16(bsrc3 + (kb), bd + 3 * 1024);                                           \
  } while (0)

#define WRITE_A(bufbase)                                                                \
  do { if (tid < 256) {                                                                 \
    union { int4 v; __hip_bfloat16 h[8]; } u;                                           \
    if (isF32) {                                                                        \
      u.h[0] = __float2bfloat16(pa0.x); u.h[1] = __float2bfloat16(pa0.y);               \
      u.h[2] = __float2bfloat16(pa0.z); u.h[3] = __float2bfloat16(pa0.w);               \
      u.h[4] = __float2bfloat16(pa1.x); u.h[5] = __float2bfloat16(pa1.y);               \
      u.h[6] = __float2bfloat16(pa1.z); u.h[7] = __float2bfloat16(pa1.w);               \
    } else {                                                                            \
      u.v.x = qb0.x; u.v.y = qb0.y; u.v.z = qb1.x; u.v.w = qb1.y;                       \
    }                                                                                   \
    *(int4*)((char*)As + (bufbase) + awoff) = u.v;                                      \
  } } while (0)

#define COMPUTE(buf)                                                                    \
  do {                                                                                  \
    const char* ab = (const char*)As + (buf) * ASB;                                     \
    const char* bb = (const char*)Bs + (buf) * BSB;                                     \
    _Pragma("unroll")                                                                   \
    for (int kk = 0; kk < 2; ++kk) {                                                    \
      const int rl = (kk * 64 + quad * 16) ^ ((lrow & 7) << 4);                         \
      bf16x8_t af0 = *(const bf16x8_t*)(ab + (0 * 16 + lrow) * 128 + rl);               \
      bf16x8_t af1 = *(const bf16x8_t*)(ab + (1 * 16 + lrow) * 128 + rl);               \
      bf16x8_t bf0 = *(const bf16x8_t*)(bb + (w * 32 + 0 * 16 + lrow) * 128 + rl);      \
      bf16x8_t bf1 = *(const bf16x8_t*)(bb + (w * 32 + 1 * 16 + lrow) * 128 + rl);      \
      acc[0][0] = __builtin_amdgcn_mfma_f32_16x16x32_bf16(af0, bf0, acc[0][0], 0, 0, 0);\
      acc[0][1] = __builtin_amdgcn_mfma_f32_16x16x32_bf16(af0, bf1, acc[0][1], 0, 0, 0);\
      acc[1][0] = __builtin_amdgcn_mfma_f32_16x16x32_bf16(af1, bf0, acc[1][0], 0, 0, 0);\
      acc[1][1] = __builtin_amdgcn_mfma_f32_16x16x32_bf16(af1, bf1, acc[1][1], 0, 0, 0);\
    }                                                                                   \
  } while (0)

  // ---- prologue: stage k-step 0 into buffer 0
  {
    const int kk0 = phase << 6;
    ISSUE_A(kk0);
    asm volatile("" ::: "memory");            // pin A-issue before B-issue (vmcnt order)
    __builtin_amdgcn_sched_barrier(0);
    STAGE_B(2 * kk0, 0);
    __builtin_amdgcn_sched_barrier(0);
    if (tid < 256) {
      asm volatile("s_waitcnt vmcnt(4)" ::: "memory");   // A(0) landed; B(0) still flying
      __builtin_amdgcn_sched_barrier(0);
      WRITE_A(0);
    }
    asm volatile("s_waitcnt lgkmcnt(0)" ::: "memory");
    __builtin_amdgcn_s_barrier();             // As[0] visible; B(0) NOT drained
  }

  int cur = 0;
  for (int t = 0; t < 31; ++t) {
    const int nk  = ((t + 1 + phase) & 31) << 6;
    const int nxt = cur ^ 1;
    // issue t+1 (A first, then B — order pinned for vmcnt math)
    ISSUE_A(nk);
    asm volatile("" ::: "memory");
    __builtin_amdgcn_sched_barrier(0);
    STAGE_B(2 * nk, nxt * BSB);
    __builtin_amdgcn_sched_barrier(0);
    // wait for B(t) only (self-staged, per-wave vmcnt); t+1's loads stay in flight
    if (tid < 256) { asm volatile("s_waitcnt vmcnt(6)" ::: "memory"); }
    else           { asm volatile("s_waitcnt vmcnt(4)" ::: "memory"); }
    __builtin_amdgcn_sched_barrier(0);
    COMPUTE(cur);
    // A(t+1) regs -> As[nxt]; only A's 2 loads waited (B(t+1)'s 4 keep flying)
    if (tid < 256) {
      asm volatile("s_waitcnt vmcnt(4)" ::: "memory");
      __builtin_amdgcn_sched_barrier(0);
      WRITE_A(nxt * ASB);
    }
    asm volatile("s_waitcnt lgkmcnt(0)" ::: "memory");
    __builtin_amdgcn_s_barrier();             // raw barrier: NO vmcnt drain
    __builtin_amdgcn_sched_barrier(0);
    cur = nxt;
  }
  // epilogue k-step 31: just drain and compute
  asm volatile("s_waitcnt vmcnt(0)" ::: "memory");
  __builtin_amdgcn_sched_barrier(0);
  COMPUTE(cur);

  // C/D layout (m89/m91-verified): row = quad*4 + reg, col = lane&15
#pragma unroll
  for (int mt = 0; mt < 2; ++mt) {
    const int mrow = bm0 + mt * 16 + quad * 4;
#pragma unroll
    for (int nt = 0; nt < 2; ++nt) {
      const int ncol = w * 32 + nt * 16 + lrow;
#pragma unroll
      for (int r = 0; r < 4; ++r)
        C[(size_t)(mrow + r) * NT + ncol] = __float2bfloat16(acc[mt][nt][r]);
    }
  }
#undef ISSUE_A
#undef STAGE_B
#undef WRITE_A
#undef COMPUTE
}

// ---------------- kernel 2: softmax-compress + RMSNorm + RoPE -------------------------
// 512 threads = 4 row-groups x 128 cols; flash-style exact merge of partial softmaxes.
__global__ __launch_bounds__(512)
void k_compress(const __hip_bfloat16* __restrict__ C,      // [MT][NT] bf16
                const void* __restrict__ pbias,            // [128][128]
                const void* __restrict__ nw,               // [128]
                const int* __restrict__ flag,
                void* __restrict__ out) {                  // [128*128]
  const int isF32 = *flag;
  const int tid = threadIdx.x;
  const int j = tid & (DDIM - 1);   // d index 0..127
  const int g = tid >> 7;           // row-group 0..3
  const int bt = blockIdx.x;        // b*64 + t
  const int t  = bt & 63;
  const long i0 = (long)bt * 128;

  float mx = -3.0e38f, l = 0.f, acc = 0.f;
#pragma unroll 8
  for (int rr = 0; rr < 32; ++rr) {
    const int r = g * 32 + rr;
    const __hip_bfloat16* row = C + (i0 + r) * NT;
    float pb = isF32 ? ((const float*)pbias)[r * DDIM + j]
                     : __bfloat162float(((const __hip_bfloat16*)pbias)[r * DDIM + j]);
    float gt = __bfloat162float(row[DDIM + j]) + pb;
    float v  = __bfloat162float(row[j]);
    float nm = fmaxf(mx, gt);
    float sc = __expf(mx - nm);
    float e  = __expf(gt - nm);
    l   = l * sc + e;
    acc = acc * sc + e * v;
    mx  = nm;
  }

  __shared__ float smx[4][DDIM], sl[4][DDIM], sa[4][DDIM];
  __shared__ float sh[DDIM];
  __shared__ float ssum[2];
  smx[g][j] = mx; sl[g][j] = l; sa[g][j] = acc;
  __syncthreads();

  float comp = 0.f;
  if (g == 0) {
    float M = fmaxf(fmaxf(smx[0][j], smx[1][j]), fmaxf(smx[2][j], smx[3][j]));
    float L = 0.f, A = 0.f;
#pragma unroll
    for (int q = 0; q < 4; ++q) {
      float s = __expf(smx[q][j] - M);
      L += sl[q][j] * s;
      A += sa[q][j] * s;
    }
    comp = A / L;
    float sq = comp * comp;
#pragma unroll
    for (int off = 32; off > 0; off >>= 1) sq += __shfl_down(sq, off, 64);
    if ((j & 63) == 0) ssum[j >> 6] = sq;
  }
  __syncthreads();

  if (g == 0) {
    float var = (ssum[0] + ssum[1]) * (1.0f / DDIM);
    float wv = isF32 ? ((const float*)nw)[j] : __bfloat162float(((const __hip_bfloat16*)nw)[j]);
    float y = comp * rsqrtf(var + 1e-6f) * wv;
    sh[j] = y;
  }
  __syncthreads();

  if (g == 0) {
    float y = sh[j];
    float outv = y;  // nope part (j < 64)
    if (j >= 64) {
      int jj = j - 64;             // rope index 0..63
      int fi = jj >> 1;            // repeat(cos,2): freq index
      double invf = exp((double)fi * (-0.28782313662425575));  // 10000^(-fi/32)
      double ang  = (double)(t * 128) * invf;
      float c = (float)cos(ang);
      float s = (float)sin(ang);
      float other = (jj < 32) ? -sh[64 + jj + 32] : sh[64 + jj - 32];  // rotate_half
      outv = y * c + other * s;
    }
    if (isF32) ((float*)out)[bt * DDIM + j] = outv;
    else       ((__hip_bfloat16*)out)[bt * DDIM + j] = __float2bfloat16(outv);
  }
}

// ---------------- host ----------------------------------------------------------------
extern "C" void kernel_launch(void* const* d_in, const int* in_sizes, int n_in,
                              void* d_out, int out_size, void* d_ws, size_t ws_size,
                              hipStream_t stream) {
  const void* hidden = d_in[0];
  // d_in[1] q_residual, d_in[2] position_ids: unused by the reference
  const void* w_kv   = d_in[3];
  const void* w_gate = d_in[4];
  const void* pbias  = d_in[5];
  const void* nw     = d_in[6];

  // ws layout: [0] flag (int), [256 B) Wt bf16 1 MiB, [256 B + 1 MiB) C bf16 8 MiB
  int* flag = (int*)d_ws;
  __hip_bfloat16* Wt = (__hip_bfloat16*)((char*)d_ws + 256);
  __hip_bfloat16* C  = (__hip_bfloat16*)((char*)d_ws + 256 + (size_t)NT * HDIM * sizeof(__hip_bfloat16));

  k_prep<<<dim3(HDIM / 64, DDIM / 64, 2), 256, 0, stream>>>(w_kv, w_gate,
                                                            (const unsigned short*)hidden, flag, Wt);
  k_gemm<<<dim3(MT / BM), 512, 0, stream>>>(hidden, Wt, flag, C);
  k_compress<<<dim3(128), 512, 0, stream>>>(C, pbias, nw, flag, d_out);
}